// Round 11
// baseline (763.892 us; speedup 1.0000x reference)
//
#include <hip/hip_runtime.h>
#include <hip/hip_bf16.h>
#include <hip/hip_fp8.h>

// LabelWiseAttn: m[b,c,d] = softmax_l(U[c,:]·x[b,l,:]) @ x[b]
// B=16 L=2048 D=512 C=8921.  Flash-style fusion, fp32 accum.
// R26 = R24 (best, 527us) with G1 in 32x32x64 MX fp8 by 4 waves (w<4, cg=w&3):
//      a 32x32 A-tile spans 32 c-rows -> 4 waves cover CTn=128, each reads the
//      16KB xk tile ONCE -> G1 LDS reads halve (128->64 b128 instrs/CU/phase).
//      C/D layout: col=lane&31(l), row=(reg&3)+8*(reg>>2)+4*(lane>>5) (m74).
//      Denominator moved to G2 dq==0 waves (w=0,4): they already read every P
//      value as pa fragments; sum bf16 pa + shfl_xor(16,32) over lg.
//      Register budget: us8 64 + S 16 + acc 128 ~ 240 <= 256 (R16/R22 calib).
//      Everything else (staging, BARV(4) ledger, XT/P buffers, G2, epilogue)
//      is R24 verbatim. R25 lesson: do NOT shrink CTn (per-phase overhead
//      amortization dies).

#define Bn 16
#define Ln 2048
#define Dn 512
#define Cn 8921
#define CPn 8960            // C padded to multiple of 64
#define CTn 128             // c-tile per workgroup
#define NCTn (CPn/CTn)      // 70
#define NWGn (Bn*NCTn)      // 1120
#define NP   (Ln/32)        // 64 pairs of 32 l

typedef __attribute__((ext_vector_type(8))) short bf16x8;
typedef __attribute__((ext_vector_type(4))) float f32x4;
typedef __attribute__((ext_vector_type(16))) float f32x16;
typedef __attribute__((ext_vector_type(4))) int i32x4;
typedef __attribute__((ext_vector_type(8))) int i32x8;

// LDS ushort offsets
#define XKu(i) ((i)*8192)              // 2 slots x 16 KB: [32 l][512 B fp8] swz16
#define XTu(i) (16384 + (i)*16384)     // 3 slots x 32 KB: [2 half][16 blk][512]
#define Pu(i)  (65536 + (i)*6144)      // 2 slots x 12 KB: [2 lhalf][128 c][24]
#define DENu   77824                   // float[128] @ byte 155648
#define P_S 24
#define LDS_BYTES 156160               // <= 160 KiB; 1 WG/CU

#define ER_S 132            // epilogue f32 stride (528 B = 0 mod 16)

__device__ __forceinline__ unsigned short f2bf(float f) {
  unsigned int u = __float_as_uint(f);
  u += 0x7fffu + ((u >> 16) & 1u);      // RNE; no NaN possible here
  return (unsigned short)(u >> 16);
}

__device__ __forceinline__ unsigned int f2fp8(float f) {
  __hip_fp8_e4m3 q(f);                  // OCP e4m3fn, RNE-saturating
  return (unsigned int)q.__x;
}

// async global->LDS, 16B/lane, dest = wave-uniform base + lane*16 (HW)
__device__ __forceinline__ void gload16(const unsigned short* g, unsigned short* l) {
  __builtin_amdgcn_global_load_lds(
      (const __attribute__((address_space(1))) unsigned int*)g,
      (__attribute__((address_space(3))) unsigned int*)l, 16, 0, 0);
}

// counted barrier: wait N outstanding VMEM + all LDS, then raw s_barrier
#define BARV(N) do {                                                          \
    asm volatile("s_waitcnt vmcnt(" #N ") lgkmcnt(0)" ::: "memory");          \
    __builtin_amdgcn_s_barrier();                                             \
    __builtin_amdgcn_sched_barrier(0);                                        \
  } while (0)

// ---- K0: U fp32 -> fp8(U*16), pad rows [8921,8960) with zeros ----
__global__ __launch_bounds__(256) void cvt_u_kernel(const float* __restrict__ U,
                                                    unsigned char* __restrict__ Ub8) {
  long long idx = ((long long)blockIdx.x * 256 + threadIdx.x) * 8;
  int c = (int)(idx >> 9);
  float f[8];
  if (c < Cn) {
    const float4* p = reinterpret_cast<const float4*>(U + idx);
    float4 a = p[0], b = p[1];
    f[0]=a.x; f[1]=a.y; f[2]=a.z; f[3]=a.w; f[4]=b.x; f[5]=b.y; f[6]=b.z; f[7]=b.w;
  } else {
    #pragma unroll
    for (int i = 0; i < 8; ++i) f[i] = 0.f;
  }
  uint2 v;
  v.x = f2fp8(f[0]*16.f) | (f2fp8(f[1]*16.f) << 8) |
        (f2fp8(f[2]*16.f) << 16) | (f2fp8(f[3]*16.f) << 24);
  v.y = f2fp8(f[4]*16.f) | (f2fp8(f[5]*16.f) << 8) |
        (f2fp8(f[6]*16.f) << 16) | (f2fp8(f[7]*16.f) << 24);
  *reinterpret_cast<uint2*>(Ub8 + idx) = v;
}

// ---- K1: x fp32 -> fp8 xb8[b][l][d] (plain row-major)
// ----     AND bf16 xt2 pre-tiled: per (b,pair) 32KB chunk laid out exactly
// ----     as the XT LDS slot ([2 half][16 blk][512 ushorts], lane*8 packing)
__global__ __launch_bounds__(256) void cvt_x_kernel(const float* __restrict__ x,
                                                    unsigned char* __restrict__ xb8,
                                                    unsigned short* __restrict__ xt2) {
  __shared__ unsigned short tile[64][72];
  int bid = blockIdx.x;
  int dtb = bid & 7, lt = (bid >> 3) & 31, b = bid >> 8;
  int t = threadIdx.x;
  int r = t >> 2, q = t & 3;                       // row 0..63, col-quarter 0..3
  size_t src_off = (((size_t)b * Ln) + (size_t)(lt*64 + r)) * Dn + dtb*64 + q*16;
  const float4* src = reinterpret_cast<const float4*>(x + src_off);
  unsigned int fb[4];
  #pragma unroll
  for (int i = 0; i < 4; ++i) {
    float4 fv = src[i];
    unsigned int w0 = (unsigned int)f2bf(fv.x) | ((unsigned int)f2bf(fv.y) << 16);
    unsigned int w1 = (unsigned int)f2bf(fv.z) | ((unsigned int)f2bf(fv.w) << 16);
    *reinterpret_cast<uint2*>(&tile[r][q*16 + i*4]) = make_uint2(w0, w1);
    fb[i] = f2fp8(fv.x) | (f2fp8(fv.y) << 8) | (f2fp8(fv.z) << 16) | (f2fp8(fv.w) << 24);
  }
  uint4 f8v; f8v.x = fb[0]; f8v.y = fb[1]; f8v.z = fb[2]; f8v.w = fb[3];
  *reinterpret_cast<uint4*>(xb8 + src_off) = f8v;      // byte addr == elem idx
  __syncthreads();
  int rd = t >> 2, lq = t & 3;                     // d-row 0..63, l-quarter
  unsigned int g[8];
  #pragma unroll
  for (int k = 0; k < 8; ++k) {
    unsigned short a0 = tile[lq*16 + 2*k    ][rd];
    unsigned short a1 = tile[lq*16 + 2*k + 1][rd];
    g[k] = (unsigned int)a0 | ((unsigned int)a1 << 16);
  }
  uint4 o0; o0.x=g[0]; o0.y=g[1]; o0.z=g[2]; o0.w=g[3];   // l+0..7
  uint4 o1; o1.x=g[4]; o1.y=g[5]; o1.z=g[6]; o1.w=g[7];   // l+8..15
  // xt2 index: d = dtb*64+rd; l-range = lt*64+lq*16 (16 consecutive l = one h)
  int P  = lt*2 + (lq >> 1);          // pair 0..63
  int h  = lq & 1;                    // 16-l half within pair
  int k2 = dtb*2 + (rd >> 5);         // 32-d block 0..15
  int xR = (rd >> 2) & 7;
  int xr = rd & 3;
  int L0 = xR*8 + ((xr*2    ) ^ (xR & 3));   // staging lane for l+0..7
  int L1 = xR*8 + ((xr*2 + 1) ^ (xR & 3));   // staging lane for l+8..15
  size_t blk = ((size_t)b * NP + P) * 16384 + (size_t)(h*16 + k2) * 512;
  *reinterpret_cast<uint4*>(xt2 + blk + L0*8) = o0;
  *reinterpret_cast<uint4*>(xt2 + blk + L1*8) = o1;
}

// ---- Fused: per WG 128 c-rows x 512 d, stream L in 32-l pairs ----
__global__ __launch_bounds__(512, 2) void fused_kernel(
    const unsigned char* __restrict__ Ub8,
    const unsigned char* __restrict__ xb8,
    const unsigned short* __restrict__ xt2,
    float* __restrict__ out) {
  extern __shared__ unsigned short lds[];
  float* den_s = reinterpret_cast<float*>(lds + DENu);  // [128]
  const unsigned char* lb = reinterpret_cast<const unsigned char*>(lds);

  int bid = blockIdx.x;
  int linear = (bid & 7) * (NWGn/8) + (bid >> 3);  // bijective XCD swizzle (1120=8*140)
  int b = linear / NCTn;
  int cblk = linear - b * NCTn;
  int c0 = cblk * CTn;

  int t = threadIdx.x;
  int lane = t & 63;
  int w = t >> 6;          // wave 0..7: G1 (w<4, cg=w&3); G2 (cq,dq)=(w>>2,w&3)
  int li = lane & 15;
  int lg = lane >> 4;
  int cg = w & 3;
  int cq = w >> 2;
  int dq = w & 3;

  const unsigned char* xb8p = xb8 + (size_t)b * Ln * Dn;
  const unsigned short* xt2p = xt2 + (size_t)b * NP * 16384;

  // ---- staging lane-consts ----
  int l5 = lane >> 5;                 // xk fp8: row sub-index per issue
  int s16 = lane & 31;                // xk fp8: dest slot16 (16B units)

  // fp8 xk: 2 issues/wave; rows rl = w*4 + 2i + l5 (0..31);
  // slot16 s of row r holds chunk16 s^(r&15): src = ((s16 ^ (rl&15)) * 16)
#define STAGE_XK(P, SLOT)                                                     \
  { _Pragma("unroll")                                                         \
    for (int i = 0; i < 2; ++i) {                                             \
      int rl = w*4 + 2*i + l5;                                                \
      gload16((const unsigned short*)(xb8p +                                  \
                  (size_t)((P)*32 + rl) * 512 +                               \
                  (size_t)(((s16 ^ (rl & 15)) * 16))),                        \
              lds + XKu(SLOT) + (w*4 + 2*i) * 256);                           \
    } }
  // xt2: 4 issues/wave, each 1KB CONTIGUOUS (pre-tiled layout)
#define STAGE_XT(P, SLOT)                                                     \
  { _Pragma("unroll")                                                         \
    for (int h = 0; h < 2; ++h)                                               \
      _Pragma("unroll")                                                       \
      for (int i = 0; i < 2; ++i) {                                           \
        int k = w*2 + i;                                                      \
        gload16(xt2p + (size_t)(P) * 16384 + (size_t)(h*16 + k) * 512 + lane*8,\
                lds + XTu(SLOT) + h*8192 + k*512);                            \
      } }

  // U fp8 fragments for MX-scaled 32x32x64: rows c0 + cg*32 + (lane&31);
  // step s8 needs 32 B/lane at K = s8*64 + (lane>>5)*32  (16 dwordx4 loads)
  i32x8 us8[8];
  {
    const unsigned char* up8 = Ub8 + (size_t)(c0 + cg*32 + (lane & 31)) * 512
                                    + (lane >> 5) * 32;
    #pragma unroll
    for (int s8 = 0; s8 < 8; ++s8) {
      i32x4 qa = *reinterpret_cast<const i32x4*>(up8 + s8*64);
      i32x4 qb = *reinterpret_cast<const i32x4*>(up8 + s8*64 + 16);
      us8[s8] = __builtin_shufflevector(qa, qb, 0, 1, 2, 3, 4, 5, 6, 7);
    }
  }
  __builtin_amdgcn_sched_barrier(0);   // pin U loads BEFORE staging (vmcnt ledger)

  // prologue: queue = [U(16), XK0(2), XT0(4)]
  STAGE_XK(0, 0);
  STAGE_XT(0, 0);

  f32x4 acc[4][8];   // c = cq*64 + rr*16 + lg*4 + j,  d = dq*128 + dt*16 + li
  #pragma unroll
  for (int i = 0; i < 4; ++i)
    #pragma unroll
    for (int j = 0; j < 8; ++j) acc[i][j] = (f32x4){0.f, 0.f, 0.f, 0.f};
  float dsumg[4];    // G2-side denominator partials (dq==0 waves only)
  #pragma unroll
  for (int j = 0; j < 4; ++j) dsumg[j] = 0.f;

  // G2 lane-const offsets
  int g2slot = (((li & 3) << 1) | (lg & 1)) ^ ((li >> 2) & 3);
  int g2off = ((lg >> 1) ? 8192 : 0) + (dq*32 + (li >> 2))*64 + g2slot*8;
  int pboff = ((lg >> 1) ? 3072 : 0) + (cq*64 + li)*P_S + (lg & 1)*8;

  BARV(4);   // U + XK(0) landed; XT(0) in flight

  int st = 1;                         // XT stage slot = (p+1)%3
  for (int p = 0; p < NP; ++p) {
    // ---- stage next: XK(p+1) 1-ahead dbuf, XT(p+1) into rotating slot ----
    if (p + 1 < NP) {
      STAGE_XK(p + 1, (p + 1) & 1);
      STAGE_XT(p + 1, st);
    }

    // ---- G1(p): 32x32x64 MX fp8, waves 0-3, from XK slot p&1 ----
    // B: col l=lane&31 (=XK row), K-half lane>>5; chunk16 cp at slot cp^(l&15)
    f32x16 S;
    #pragma unroll
    for (int i = 0; i < 16; ++i) S[i] = 0.f;
    if (w < 4) {
      const unsigned char* x0 = lb + (p & 1) * 16384 + (lane & 31) * 512;
      int lh2 = (lane >> 5) * 2;
      __builtin_amdgcn_s_setprio(1);
      #pragma unroll
      for (int s8 = 0; s8 < 8; ++s8) {
        int cp = s8*4 + lh2;
        int o0 = ((cp    ) ^ (lane & 15)) * 16;
        int o1 = ((cp + 1) ^ (lane & 15)) * 16;
        i32x4 qa = *reinterpret_cast<const i32x4*>(x0 + o0);
        i32x4 qb = *reinterpret_cast<const i32x4*>(x0 + o1);
        i32x8 bv = __builtin_shufflevector(qa, qb, 0, 1, 2, 3, 4, 5, 6, 7);
        S = __builtin_amdgcn_mfma_scale_f32_32x32x64_f8f6f4(
                us8[s8], bv, S, 0, 0, 0, 0x7F7F7F7F, 0, 0x7F7F7F7F);
      }
      __builtin_amdgcn_s_setprio(0);
    }

    // ---- G2(p-1): bf16 GEMM2 from XT slot (p-1)%3 + P slot (p-1)&1 ----
    if (p > 0) {
      int xtrd = (st == 2) ? 0 : st + 1;       // (p-1)%3 == (st+1)%3
      const unsigned short* xbase = lds + XTu(xtrd) + g2off;
      const unsigned short* pws = lds + Pu((p - 1) & 1) + pboff;
      bf16x8 pa[4];
      #pragma unroll
      for (int rr = 0; rr < 4; ++rr)
        pa[rr] = *reinterpret_cast<const bf16x8*>(pws + rr*16*P_S);
      if (dq == 0) {                 // denominator: sum this wave's pa slice
        #pragma unroll
        for (int rr = 0; rr < 4; ++rr)
          #pragma unroll
          for (int j = 0; j < 8; ++j)
            dsumg[rr] += __uint_as_float(
                (unsigned int)(unsigned short)pa[rr][j] << 16);
      }
      __builtin_amdgcn_s_setprio(1);
      #pragma unroll
      for (int dt = 0; dt < 8; ++dt) {
        bf16x8 bv = *reinterpret_cast<const bf16x8*>(xbase + dt*256);
        #pragma unroll
        for (int rr = 0; rr < 4; ++rr)
          acc[rr][dt] = __builtin_amdgcn_mfma_f32_16x16x32_bf16(
              pa[rr], bv, acc[rr][dt], 0, 0, 0);
      }
      __builtin_amdgcn_s_setprio(0);
    }

    // ---- softmax-finish(p) -> P slot p&1 (waves 0-3, 16 rows each) ----
    if (w < 4) {
      unsigned short* pw = lds + Pu(p & 1) + ((lane >> 4) & 1) * 3072;
      int lh = lane >> 5;
      int lcol = lane & 15;
      #pragma unroll
      for (int i = 0; i < 16; ++i) {
        int r = (i & 3) + 8*(i >> 2) + 4*lh;
        float pv = __expf(S[i] * 0.0625f);   // undo U*16
        pw[(cg*32 + r)*P_S + lcol] = f2bf(pv);
      }
    }

    // ---- single barrier per pair ----
    if (p + 1 < NP) { BARV(4); } else { BARV(0); }
    st = (st == 2) ? 0 : st + 1;
  }

  // ---- post-loop G2(NP-1): XT slot (NP-1)%3 = 0, P slot (NP-1)&1 = 1 ----
  {
    const unsigned short* xbase = lds + XTu(0) + g2off;
    const unsigned short* pws = lds + Pu(1) + pboff;
    bf16x8 pa[4];
    #pragma unroll
    for (int rr = 0; rr < 4; ++rr)
      pa[rr] = *reinterpret_cast<const bf16x8*>(pws + rr*16*P_S);
    if (dq == 0) {
      #pragma unroll
      for (int rr = 0; rr < 4; ++rr)
        #pragma unroll
        for (int j = 0; j < 8; ++j)
          dsumg[rr] += __uint_as_float(
              (unsigned int)(unsigned short)pa[rr][j] << 16);
    }
    __builtin_amdgcn_s_setprio(1);
    #pragma unroll
    for (int dt = 0; dt < 8; ++dt) {
      bf16x8 bv = *reinterpret_cast<const bf16x8*>(xbase + dt*256);
      #pragma unroll
      for (int rr = 0; rr < 4; ++rr)
        acc[rr][dt] = __builtin_amdgcn_mfma_f32_16x16x32_bf16(
            pa[rr], bv, acc[rr][dt], 0, 0, 0);
    }
    __builtin_amdgcn_s_setprio(0);
  }

  // denom: dq==0 waves hold row sums over their l-slices; reduce over lg
  if (dq == 0) {
    #pragma unroll
    for (int rr = 0; rr < 4; ++rr) {
      dsumg[rr] += __shfl_xor(dsumg[rr], 16, 64);
      dsumg[rr] += __shfl_xor(dsumg[rr], 32, 64);
      if (lg == 0) den_s[cq*64 + rr*16 + li] = dsumg[rr];
    }
  }
  __syncthreads();   // den ready; all G2 LDS reads done

  // epilogue: divide, per-wave LDS transpose (dead xk/xt area), 512B stores
  {
    float* er = reinterpret_cast<float*>(lds) + w * (16 * ER_S);
    int csub0 = lane >> 5;          // 0..1
    int dcol = (lane & 31) * 4;
    #pragma unroll
    for (int rr = 0; rr < 4; ++rr) {
      __syncthreads();   // er region free
      #pragma unroll
      for (int j = 0; j < 4; ++j) {
        int row = lg*4 + j;
        float inv = 1.0f / den_s[cq*64 + rr*16 + row];
        #pragma unroll
        for (int dt = 0; dt < 8; ++dt)
          er[row*ER_S + dt*16 + li] = acc[rr][dt][j] * inv;
      }
      __syncthreads();   // er ready
      #pragma unroll
      for (int it = 0; it < 8; ++it) {
        int crow = it*2 + csub0;
        float4 v = *reinterpret_cast<const float4*>(&er[crow*ER_S + dcol]);
        int c = c0 + cq*64 + rr*16 + crow;
        if (c < Cn)
          *reinterpret_cast<float4*>(out + ((size_t)b*Cn + c)*Dn + dq*128 + dcol) = v;
      }
    }
  }
}

extern "C" void kernel_launch(void* const* d_in, const int* in_sizes, int n_in,
                              void* d_out, int out_size, void* d_ws, size_t ws_size,
                              hipStream_t stream) {
  const float* x = (const float*)d_in[0];
  const float* U = (const float*)d_in[1];
  float* out = (float*)d_out;

  // ws layout: Ub8[8960*512 B] | xb8[16*2048*512 B] | xt2 bf16[16*64*16384] ~ 53 MB
  unsigned char* Ub8 = (unsigned char*)d_ws;
  unsigned char* xb8 = Ub8 + (size_t)CPn * Dn;
  unsigned short* xt2 = (unsigned short*)(xb8 + (size_t)Bn * Ln * Dn);

  hipFuncSetAttribute((const void*)fused_kernel,
                      hipFuncAttributeMaxDynamicSharedMemorySize, LDS_BYTES);

  cvt_u_kernel<<<(CPn*Dn)/(256*8), 256, 0, stream>>>(U, Ub8);
  cvt_x_kernel<<<Bn*32*8, 256, 0, stream>>>(x, xb8, xt2);
  fused_kernel<<<NWGn, 512, LDS_BYTES, stream>>>(Ub8, xb8, xt2, out);
}

// Round 12
// 529.151 us; speedup vs baseline: 1.4436x; 1.4436x over previous
//
#include <hip/hip_runtime.h>
#include <hip/hip_bf16.h>
#include <hip/hip_fp8.h>

// LabelWiseAttn: m[b,c,d] = softmax_l(U[c,:]·x[b,l,:]) @ x[b]
// B=16 L=2048 D=512 C=8921.  Flash-style fusion, fp32 accum.
// R27 = R24 exact revert (best verified: 527.6us).
//      G1: MX-scaled fp8 K=128 from XK LDS, 16B-granular swizzle
//      (slot16 s of row r holds chunk16 s^(r&15); staging src
//      ((lane&31)^(r&15))*16 contiguous, no pre-swap), 2x ds_read_b128
//      per s-step per half -- 32 banks x 2-way = free.
//      G2: bf16 16x16x32 from XT LDS (pre-tiled xt2, 1KB contiguous loads).
//      Phase p: {stage XK(p+1),XT(p+1); G1(p); G2(p-1); softmax(p); BARV(4)}.
//      Lessons encoded: R16/R22/R26 -- resident state > ~250 regs spills
//      (512 regs/SIMD-slot; 2 waves/SIMD is this kernel's ceiling).
//      R23 -- G1 operands must be LDS-prefetched, not global-direct.
//      R25 -- CTn < 128 dies on per-phase overhead amortization.
//      R26 -- 32x32 G1 needs 64 U-regs resident -> spill; unfundable.

#define Bn 16
#define Ln 2048
#define Dn 512
#define Cn 8921
#define CPn 8960            // C padded to multiple of 64
#define CTn 128             // c-tile per workgroup
#define NCTn (CPn/CTn)      // 70
#define NWGn (Bn*NCTn)      // 1120
#define NP   (Ln/32)        // 64 pairs of 32 l

typedef __attribute__((ext_vector_type(8))) short bf16x8;
typedef __attribute__((ext_vector_type(4))) float f32x4;
typedef __attribute__((ext_vector_type(4))) int i32x4;
typedef __attribute__((ext_vector_type(8))) int i32x8;

// LDS ushort offsets
#define XKu(i) ((i)*8192)              // 2 slots x 16 KB: [32 l][512 B fp8] swz16
#define XTu(i) (16384 + (i)*16384)     // 3 slots x 32 KB: [2 half][16 blk][512]
#define Pu(i)  (65536 + (i)*6144)      // 2 slots x 12 KB: [2 half][128 c][24]
#define DENu   77824                   // float[128] @ byte 155648
#define P_S 24
#define LDS_BYTES 156160               // <= 160 KiB; 1 WG/CU

#define ER_S 132            // epilogue f32 stride (528 B = 0 mod 16)

__device__ __forceinline__ unsigned short f2bf(float f) {
  unsigned int u = __float_as_uint(f);
  u += 0x7fffu + ((u >> 16) & 1u);      // RNE; no NaN possible here
  return (unsigned short)(u >> 16);
}

__device__ __forceinline__ unsigned int f2fp8(float f) {
  __hip_fp8_e4m3 q(f);                  // OCP e4m3fn, RNE-saturating
  return (unsigned int)q.__x;
}

// async global->LDS, 16B/lane, dest = wave-uniform base + lane*16 (HW)
__device__ __forceinline__ void gload16(const unsigned short* g, unsigned short* l) {
  __builtin_amdgcn_global_load_lds(
      (const __attribute__((address_space(1))) unsigned int*)g,
      (__attribute__((address_space(3))) unsigned int*)l, 16, 0, 0);
}

// counted barrier: wait N outstanding VMEM + all LDS, then raw s_barrier
#define BARV(N) do {                                                          \
    asm volatile("s_waitcnt vmcnt(" #N ") lgkmcnt(0)" ::: "memory");          \
    __builtin_amdgcn_s_barrier();                                             \
    __builtin_amdgcn_sched_barrier(0);                                        \
  } while (0)

// ---- K0: U fp32 -> fp8(U*16), pad rows [8921,8960) with zeros ----
__global__ __launch_bounds__(256) void cvt_u_kernel(const float* __restrict__ U,
                                                    unsigned char* __restrict__ Ub8) {
  long long idx = ((long long)blockIdx.x * 256 + threadIdx.x) * 8;
  int c = (int)(idx >> 9);
  float f[8];
  if (c < Cn) {
    const float4* p = reinterpret_cast<const float4*>(U + idx);
    float4 a = p[0], b = p[1];
    f[0]=a.x; f[1]=a.y; f[2]=a.z; f[3]=a.w; f[4]=b.x; f[5]=b.y; f[6]=b.z; f[7]=b.w;
  } else {
    #pragma unroll
    for (int i = 0; i < 8; ++i) f[i] = 0.f;
  }
  uint2 v;
  v.x = f2fp8(f[0]*16.f) | (f2fp8(f[1]*16.f) << 8) |
        (f2fp8(f[2]*16.f) << 16) | (f2fp8(f[3]*16.f) << 24);
  v.y = f2fp8(f[4]*16.f) | (f2fp8(f[5]*16.f) << 8) |
        (f2fp8(f[6]*16.f) << 16) | (f2fp8(f[7]*16.f) << 24);
  *reinterpret_cast<uint2*>(Ub8 + idx) = v;
}

// ---- K1: x fp32 -> fp8 xb8[b][l][d] (plain row-major)
// ----     AND bf16 xt2 pre-tiled: per (b,pair) 32KB chunk laid out exactly
// ----     as the XT LDS slot ([2 half][16 blk][512 ushorts], lane*8 packing)
__global__ __launch_bounds__(256) void cvt_x_kernel(const float* __restrict__ x,
                                                    unsigned char* __restrict__ xb8,
                                                    unsigned short* __restrict__ xt2) {
  __shared__ unsigned short tile[64][72];
  int bid = blockIdx.x;
  int dtb = bid & 7, lt = (bid >> 3) & 31, b = bid >> 8;
  int t = threadIdx.x;
  int r = t >> 2, q = t & 3;                       // row 0..63, col-quarter 0..3
  size_t src_off = (((size_t)b * Ln) + (size_t)(lt*64 + r)) * Dn + dtb*64 + q*16;
  const float4* src = reinterpret_cast<const float4*>(x + src_off);
  unsigned int fb[4];
  #pragma unroll
  for (int i = 0; i < 4; ++i) {
    float4 fv = src[i];
    unsigned int w0 = (unsigned int)f2bf(fv.x) | ((unsigned int)f2bf(fv.y) << 16);
    unsigned int w1 = (unsigned int)f2bf(fv.z) | ((unsigned int)f2bf(fv.w) << 16);
    *reinterpret_cast<uint2*>(&tile[r][q*16 + i*4]) = make_uint2(w0, w1);
    fb[i] = f2fp8(fv.x) | (f2fp8(fv.y) << 8) | (f2fp8(fv.z) << 16) | (f2fp8(fv.w) << 24);
  }
  uint4 f8v; f8v.x = fb[0]; f8v.y = fb[1]; f8v.z = fb[2]; f8v.w = fb[3];
  *reinterpret_cast<uint4*>(xb8 + src_off) = f8v;      // byte addr == elem idx
  __syncthreads();
  int rd = t >> 2, lq = t & 3;                     // d-row 0..63, l-quarter
  unsigned int g[8];
  #pragma unroll
  for (int k = 0; k < 8; ++k) {
    unsigned short a0 = tile[lq*16 + 2*k    ][rd];
    unsigned short a1 = tile[lq*16 + 2*k + 1][rd];
    g[k] = (unsigned int)a0 | ((unsigned int)a1 << 16);
  }
  uint4 o0; o0.x=g[0]; o0.y=g[1]; o0.z=g[2]; o0.w=g[3];   // l+0..7
  uint4 o1; o1.x=g[4]; o1.y=g[5]; o1.z=g[6]; o1.w=g[7];   // l+8..15
  // xt2 index: d = dtb*64+rd; l-range = lt*64+lq*16 (16 consecutive l = one h)
  int P  = lt*2 + (lq >> 1);          // pair 0..63
  int h  = lq & 1;                    // 16-l half within pair
  int k2 = dtb*2 + (rd >> 5);         // 32-d block 0..15
  int xR = (rd >> 2) & 7;
  int xr = rd & 3;
  int L0 = xR*8 + ((xr*2    ) ^ (xR & 3));   // staging lane for l+0..7
  int L1 = xR*8 + ((xr*2 + 1) ^ (xR & 3));   // staging lane for l+8..15
  size_t blk = ((size_t)b * NP + P) * 16384 + (size_t)(h*16 + k2) * 512;
  *reinterpret_cast<uint4*>(xt2 + blk + L0*8) = o0;
  *reinterpret_cast<uint4*>(xt2 + blk + L1*8) = o1;
}

// ---- Fused: per WG 128 c-rows x 512 d, stream L in 32-l pairs ----
__global__ __launch_bounds__(512, 2) void fused_kernel(
    const unsigned char* __restrict__ Ub8,
    const unsigned char* __restrict__ xb8,
    const unsigned short* __restrict__ xt2,
    float* __restrict__ out) {
  extern __shared__ unsigned short lds[];
  float* den_s = reinterpret_cast<float*>(lds + DENu);  // [128]
  const unsigned char* lb = reinterpret_cast<const unsigned char*>(lds);

  int bid = blockIdx.x;
  int linear = (bid & 7) * (NWGn/8) + (bid >> 3);  // bijective XCD swizzle (1120=8*140)
  int b = linear / NCTn;
  int cblk = linear - b * NCTn;
  int c0 = cblk * CTn;

  int t = threadIdx.x;
  int lane = t & 63;
  int w = t >> 6;          // wave 0..7: G1 c-eighth; G2 (cq,dq)=(w>>2,w&3)
  int li = lane & 15;
  int lg = lane >> 4;
  int cq = w >> 2;
  int dq = w & 3;

  const unsigned char* xb8p = xb8 + (size_t)b * Ln * Dn;
  const unsigned short* xt2p = xt2 + (size_t)b * NP * 16384;

  // ---- staging lane-consts ----
  int l5 = lane >> 5;                 // xk fp8: row sub-index per issue
  int s16 = lane & 31;                // xk fp8: dest slot16 (16B units)

  // fp8 xk: 2 issues/wave; rows rl = w*4 + 2i + l5 (0..31);
  // slot16 s of row r holds chunk16 s^(r&15): src = ((s16 ^ (rl&15)) * 16)
#define STAGE_XK(P, SLOT)                                                     \
  { _Pragma("unroll")                                                         \
    for (int i = 0; i < 2; ++i) {                                             \
      int rl = w*4 + 2*i + l5;                                                \
      gload16((const unsigned short*)(xb8p +                                  \
                  (size_t)((P)*32 + rl) * 512 +                               \
                  (size_t)(((s16 ^ (rl & 15)) * 16))),                        \
              lds + XKu(SLOT) + (w*4 + 2*i) * 256);                           \
    } }
  // xt2: 4 issues/wave, each 1KB CONTIGUOUS (pre-tiled layout)
#define STAGE_XT(P, SLOT)                                                     \
  { _Pragma("unroll")                                                         \
    for (int h = 0; h < 2; ++h)                                               \
      _Pragma("unroll")                                                       \
      for (int i = 0; i < 2; ++i) {                                           \
        int k = w*2 + i;                                                      \
        gload16(xt2p + (size_t)(P) * 16384 + (size_t)(h*16 + k) * 512 + lane*8,\
                lds + XTu(SLOT) + h*8192 + k*512);                            \
      } }

  // U fp8 fragments for MX-scaled 16x16x128: rows c0 + w*16 + li;
  // step s needs 32 B/lane at K = s*128 + lg*32  (8 x dwordx4 loads)
  i32x8 us[4];
  {
    const unsigned char* up8 = Ub8 + (size_t)(c0 + w*16 + li) * 512;
    #pragma unroll
    for (int s = 0; s < 4; ++s) {
      i32x4 qa = *reinterpret_cast<const i32x4*>(up8 + s*128 + lg*32);
      i32x4 qb = *reinterpret_cast<const i32x4*>(up8 + s*128 + lg*32 + 16);
      us[s] = __builtin_shufflevector(qa, qb, 0, 1, 2, 3, 4, 5, 6, 7);
    }
  }
  __builtin_amdgcn_sched_barrier(0);   // pin U loads BEFORE staging (vmcnt ledger)

  // prologue: queue = [U(8), XK0(2), XT0(4)]
  STAGE_XK(0, 0);
  STAGE_XT(0, 0);

  f32x4 acc[4][8];   // c = cq*64 + rr*16 + lg*4 + j,  d = dq*128 + dt*16 + li
  #pragma unroll
  for (int i = 0; i < 4; ++i)
    #pragma unroll
    for (int j = 0; j < 8; ++j) acc[i][j] = (f32x4){0.f, 0.f, 0.f, 0.f};
  float dsum[4];
  #pragma unroll
  for (int j = 0; j < 4; ++j) dsum[j] = 0.f;

  // G2 lane-const offsets
  int g2slot = (((li & 3) << 1) | (lg & 1)) ^ ((li >> 2) & 3);
  int g2off = ((lg >> 1) ? 8192 : 0) + (dq*32 + (li >> 2))*64 + g2slot*8;
  int pboff = ((lg >> 1) ? 3072 : 0) + (cq*64 + li)*P_S + (lg & 1)*8;

  BARV(4);   // U + XK(0) landed; XT(0) in flight

  int st = 1;                         // XT stage slot = (p+1)%3
  for (int p = 0; p < NP; ++p) {
    // ---- stage next: XK(p+1) 1-ahead dbuf, XT(p+1) into rotating slot ----
    if (p + 1 < NP) {
      STAGE_XK(p + 1, (p + 1) & 1);
      STAGE_XT(p + 1, st);
    }

    // ---- G1(p): MX-scaled fp8 (4 K-steps of 128) from XK slot p&1 ----
    // chunks16 cp,cp+1 read as 2x ds_read_b128 at slots (cp^li), ((cp+1)^li):
    // quarter-wave = 16 distinct 16B slots = 32 banks x 2-way = free
    f32x4 a0 = (f32x4){0.f,0.f,0.f,0.f}, a1 = a0;
    {
      const unsigned char* x0 = lb + (p & 1) * 16384 + li*512;   // row li (l 0-15)
      const unsigned char* x1 = x0 + 8192;                       // row li+16
      __builtin_amdgcn_s_setprio(1);
      #pragma unroll
      for (int s = 0; s < 4; ++s) {
        int cp = s*8 + lg*2;                   // base chunk16 (16B units)
        int o0 = ((cp    ) ^ li) * 16;
        int o1 = ((cp + 1) ^ li) * 16;
        i32x4 qa0 = *reinterpret_cast<const i32x4*>(x0 + o0);
        i32x4 qb0 = *reinterpret_cast<const i32x4*>(x0 + o1);
        i32x8 bv0 = __builtin_shufflevector(qa0, qb0, 0, 1, 2, 3, 4, 5, 6, 7);
        a0 = __builtin_amdgcn_mfma_scale_f32_16x16x128_f8f6f4(
                 us[s], bv0, a0, 0, 0, 0, 0x7F7F7F7F, 0, 0x7F7F7F7F);
        i32x4 qa1 = *reinterpret_cast<const i32x4*>(x1 + o0);
        i32x4 qb1 = *reinterpret_cast<const i32x4*>(x1 + o1);
        i32x8 bv1 = __builtin_shufflevector(qa1, qb1, 0, 1, 2, 3, 4, 5, 6, 7);
        a1 = __builtin_amdgcn_mfma_scale_f32_16x16x128_f8f6f4(
                 us[s], bv1, a1, 0, 0, 0, 0x7F7F7F7F, 0, 0x7F7F7F7F);
      }
      __builtin_amdgcn_s_setprio(0);
    }

    // ---- G2(p-1): bf16 GEMM2 from XT slot (p-1)%3 + P slot (p-1)&1 ----
    if (p > 0) {
      int xtrd = (st == 2) ? 0 : st + 1;       // (p-1)%3 == (st+1)%3
      const unsigned short* xbase = lds + XTu(xtrd) + g2off;
      const unsigned short* pws = lds + Pu((p - 1) & 1) + pboff;
      bf16x8 pa[4];
      #pragma unroll
      for (int rr = 0; rr < 4; ++rr)
        pa[rr] = *reinterpret_cast<const bf16x8*>(pws + rr*16*P_S);
      __builtin_amdgcn_s_setprio(1);
      #pragma unroll
      for (int dt = 0; dt < 8; ++dt) {
        bf16x8 bv = *reinterpret_cast<const bf16x8*>(xbase + dt*256);
        #pragma unroll
        for (int rr = 0; rr < 4; ++rr)
          acc[rr][dt] = __builtin_amdgcn_mfma_f32_16x16x32_bf16(
              pa[rr], bv, acc[rr][dt], 0, 0, 0);
      }
      __builtin_amdgcn_s_setprio(0);
    }

    // ---- softmax-finish(p) -> P slot p&1 ----
    {
      unsigned short* pw0 = lds + Pu(p & 1);
      unsigned short* pw1 = pw0 + 3072;
      #pragma unroll
      for (int j = 0; j < 4; ++j) {
        float pv0 = __expf(a0[j] * 0.0625f);   // undo U*16
        float pv1 = __expf(a1[j] * 0.0625f);
        dsum[j] += pv0 + pv1;
        pw0[(w*16 + lg*4 + j)*P_S + li] = f2bf(pv0);
        pw1[(w*16 + lg*4 + j)*P_S + li] = f2bf(pv1);
      }
    }

    // ---- single barrier per pair ----
    if (p + 1 < NP) { BARV(4); } else { BARV(0); }
    st = (st == 2) ? 0 : st + 1;
  }

  // ---- post-loop G2(NP-1): XT slot (NP-1)%3 = 0, P slot (NP-1)&1 = 1 ----
  {
    const unsigned short* xbase = lds + XTu(0) + g2off;
    const unsigned short* pws = lds + Pu(1) + pboff;
    bf16x8 pa[4];
    #pragma unroll
    for (int rr = 0; rr < 4; ++rr)
      pa[rr] = *reinterpret_cast<const bf16x8*>(pws + rr*16*P_S);
    __builtin_amdgcn_s_setprio(1);
    #pragma unroll
    for (int dt = 0; dt < 8; ++dt) {
      bf16x8 bv = *reinterpret_cast<const bf16x8*>(xbase + dt*256);
      #pragma unroll
      for (int rr = 0; rr < 4; ++rr)
        acc[rr][dt] = __builtin_amdgcn_mfma_f32_16x16x32_bf16(
            pa[rr], bv, acc[rr][dt], 0, 0, 0);
    }
    __builtin_amdgcn_s_setprio(0);
  }

  // denom: reduce over 16 l-lanes (li bits); each wave owns its 16 c rows
  #pragma unroll
  for (int m = 1; m < 16; m <<= 1)
    #pragma unroll
    for (int j = 0; j < 4; ++j)
      dsum[j] += __shfl_xor(dsum[j], m, 64);
  if (li == 0) {
    #pragma unroll
    for (int j = 0; j < 4; ++j)
      den_s[w*16 + lg*4 + j] = dsum[j];
  }
  __syncthreads();   // den ready; all G2 LDS reads done

  // epilogue: divide, per-wave LDS transpose (dead xk/xt area), 512B stores
  {
    float* er = reinterpret_cast<float*>(lds) + w * (16 * ER_S);
    int csub0 = lane >> 5;          // 0..1
    int dcol = (lane & 31) * 4;
    #pragma unroll
    for (int rr = 0; rr < 4; ++rr) {
      __syncthreads();   // er region free
      #pragma unroll
      for (int j = 0; j < 4; ++j) {
        int row = lg*4 + j;
        float inv = 1.0f / den_s[cq*64 + rr*16 + row];
        #pragma unroll
        for (int dt = 0; dt < 8; ++dt)
          er[row*ER_S + dt*16 + li] = acc[rr][dt][j] * inv;
      }
      __syncthreads();   // er ready
      #pragma unroll
      for (int it = 0; it < 8; ++it) {
        int crow = it*2 + csub0;
        float4 v = *reinterpret_cast<const float4*>(&er[crow*ER_S + dcol]);
        int c = c0 + cq*64 + rr*16 + crow;
        if (c < Cn)
          *reinterpret_cast<float4*>(out + ((size_t)b*Cn + c)*Dn + dq*128 + dcol) = v;
      }
    }
  }
}

extern "C" void kernel_launch(void* const* d_in, const int* in_sizes, int n_in,
                              void* d_out, int out_size, void* d_ws, size_t ws_size,
                              hipStream_t stream) {
  const float* x = (const float*)d_in[0];
  const float* U = (const float*)d_in[1];
  float* out = (float*)d_out;

  // ws layout: Ub8[8960*512 B] | xb8[16*2048*512 B] | xt2 bf16[16*64*16384] ~ 53 MB
  unsigned char* Ub8 = (unsigned char*)d_ws;
  unsigned char* xb8 = Ub8 + (size_t)CPn * Dn;
  unsigned short* xt2 = (unsigned short*)(xb8 + (size_t)Bn * Ln * Dn);

  hipFuncSetAttribute((const void*)fused_kernel,
                      hipFuncAttributeMaxDynamicSharedMemorySize, LDS_BYTES);

  cvt_u_kernel<<<(CPn*Dn)/(256*8), 256, 0, stream>>>(U, Ub8);
  cvt_x_kernel<<<Bn*32*8, 256, 0, stream>>>(x, xb8, xt2);
  fused_kernel<<<NWGn, 512, LDS_BYTES, stream>>>(Ub8, xb8, xt2, out);
}

// Round 14
// 526.174 us; speedup vs baseline: 1.4518x; 1.0057x over previous
//
#include <hip/hip_runtime.h>
#include <hip/hip_bf16.h>
#include <hip/hip_fp8.h>

// LabelWiseAttn: m[b,c,d] = softmax_l(U[c,:]·x[b,l,:]) @ x[b]
// B=16 L=2048 D=512 C=8921.  Flash-style fusion, fp32 accum.
// R29 = R27/R24 exact revert (best verified: 527.6-529us).
//      G1: MX-scaled fp8 K=128 from XK LDS, 16B-granular swizzle
//      (slot16 s of row r holds chunk16 s^(r&15); staging src
//      ((lane&31)^(r&15))*16 contiguous), 2x ds_read_b128 per s-step per
//      half -- 32 banks x 2-way = free.
//      G2: bf16 16x16x32 from XT LDS (pre-tiled xt2, 1KB contiguous loads).
//      Phase p: {stage XK(p+1),XT(p+1); G1(p); G2(p-1); softmax(p); BARV(4)}.
//      Search boundary (all probed): R16/R22 occupancy>2waves/SIMD = spill
//      (512 regs/SIMD-slot); R23 global-direct G1 = L2 latency on MFMA
//      chain; R25 CTn<128 = amortization death; R26 32x32 G1 = 64 U-regs =
//      spill; R28 fp8 G2 = absmax 5.9e-3 > threshold 2.6e-3 (current
//      2.44e-3 leaves no precision headroom). This is the local optimum.

#define Bn 16
#define Ln 2048
#define Dn 512
#define Cn 8921
#define CPn 8960            // C padded to multiple of 64
#define CTn 128             // c-tile per workgroup
#define NCTn (CPn/CTn)      // 70
#define NWGn (Bn*NCTn)      // 1120
#define NP   (Ln/32)        // 64 pairs of 32 l

typedef __attribute__((ext_vector_type(8))) short bf16x8;
typedef __attribute__((ext_vector_type(4))) float f32x4;
typedef __attribute__((ext_vector_type(4))) int i32x4;
typedef __attribute__((ext_vector_type(8))) int i32x8;

// LDS ushort offsets
#define XKu(i) ((i)*8192)              // 2 slots x 16 KB: [32 l][512 B fp8] swz16
#define XTu(i) (16384 + (i)*16384)     // 3 slots x 32 KB: [2 half][16 blk][512]
#define Pu(i)  (65536 + (i)*6144)      // 2 slots x 12 KB: [2 half][128 c][24]
#define DENu   77824                   // float[128] @ byte 155648
#define P_S 24
#define LDS_BYTES 156160               // <= 160 KiB; 1 WG/CU

#define ER_S 132            // epilogue f32 stride (528 B = 0 mod 16)

__device__ __forceinline__ unsigned short f2bf(float f) {
  unsigned int u = __float_as_uint(f);
  u += 0x7fffu + ((u >> 16) & 1u);      // RNE; no NaN possible here
  return (unsigned short)(u >> 16);
}

__device__ __forceinline__ unsigned int f2fp8(float f) {
  __hip_fp8_e4m3 q(f);                  // OCP e4m3fn, RNE-saturating
  return (unsigned int)q.__x;
}

// async global->LDS, 16B/lane, dest = wave-uniform base + lane*16 (HW)
__device__ __forceinline__ void gload16(const unsigned short* g, unsigned short* l) {
  __builtin_amdgcn_global_load_lds(
      (const __attribute__((address_space(1))) unsigned int*)g,
      (__attribute__((address_space(3))) unsigned int*)l, 16, 0, 0);
}

// counted barrier: wait N outstanding VMEM + all LDS, then raw s_barrier
#define BARV(N) do {                                                          \
    asm volatile("s_waitcnt vmcnt(" #N ") lgkmcnt(0)" ::: "memory");          \
    __builtin_amdgcn_s_barrier();                                             \
    __builtin_amdgcn_sched_barrier(0);                                        \
  } while (0)

// ---- K0: U fp32 -> fp8(U*16), pad rows [8921,8960) with zeros ----
__global__ __launch_bounds__(256) void cvt_u_kernel(const float* __restrict__ U,
                                                    unsigned char* __restrict__ Ub8) {
  long long idx = ((long long)blockIdx.x * 256 + threadIdx.x) * 8;
  int c = (int)(idx >> 9);
  float f[8];
  if (c < Cn) {
    const float4* p = reinterpret_cast<const float4*>(U + idx);
    float4 a = p[0], b = p[1];
    f[0]=a.x; f[1]=a.y; f[2]=a.z; f[3]=a.w; f[4]=b.x; f[5]=b.y; f[6]=b.z; f[7]=b.w;
  } else {
    #pragma unroll
    for (int i = 0; i < 8; ++i) f[i] = 0.f;
  }
  uint2 v;
  v.x = f2fp8(f[0]*16.f) | (f2fp8(f[1]*16.f) << 8) |
        (f2fp8(f[2]*16.f) << 16) | (f2fp8(f[3]*16.f) << 24);
  v.y = f2fp8(f[4]*16.f) | (f2fp8(f[5]*16.f) << 8) |
        (f2fp8(f[6]*16.f) << 16) | (f2fp8(f[7]*16.f) << 24);
  *reinterpret_cast<uint2*>(Ub8 + idx) = v;
}

// ---- K1: x fp32 -> fp8 xb8[b][l][d] (plain row-major)
// ----     AND bf16 xt2 pre-tiled: per (b,pair) 32KB chunk laid out exactly
// ----     as the XT LDS slot ([2 half][16 blk][512 ushorts], lane*8 packing)
__global__ __launch_bounds__(256) void cvt_x_kernel(const float* __restrict__ x,
                                                    unsigned char* __restrict__ xb8,
                                                    unsigned short* __restrict__ xt2) {
  __shared__ unsigned short tile[64][72];
  int bid = blockIdx.x;
  int dtb = bid & 7, lt = (bid >> 3) & 31, b = bid >> 8;
  int t = threadIdx.x;
  int r = t >> 2, q = t & 3;                       // row 0..63, col-quarter 0..3
  size_t src_off = (((size_t)b * Ln) + (size_t)(lt*64 + r)) * Dn + dtb*64 + q*16;
  const float4* src = reinterpret_cast<const float4*>(x + src_off);
  unsigned int fb[4];
  #pragma unroll
  for (int i = 0; i < 4; ++i) {
    float4 fv = src[i];
    unsigned int w0 = (unsigned int)f2bf(fv.x) | ((unsigned int)f2bf(fv.y) << 16);
    unsigned int w1 = (unsigned int)f2bf(fv.z) | ((unsigned int)f2bf(fv.w) << 16);
    *reinterpret_cast<uint2*>(&tile[r][q*16 + i*4]) = make_uint2(w0, w1);
    fb[i] = f2fp8(fv.x) | (f2fp8(fv.y) << 8) | (f2fp8(fv.z) << 16) | (f2fp8(fv.w) << 24);
  }
  uint4 f8v; f8v.x = fb[0]; f8v.y = fb[1]; f8v.z = fb[2]; f8v.w = fb[3];
  *reinterpret_cast<uint4*>(xb8 + src_off) = f8v;      // byte addr == elem idx
  __syncthreads();
  int rd = t >> 2, lq = t & 3;                     // d-row 0..63, l-quarter
  unsigned int g[8];
  #pragma unroll
  for (int k = 0; k < 8; ++k) {
    unsigned short a0 = tile[lq*16 + 2*k    ][rd];
    unsigned short a1 = tile[lq*16 + 2*k + 1][rd];
    g[k] = (unsigned int)a0 | ((unsigned int)a1 << 16);
  }
  uint4 o0; o0.x=g[0]; o0.y=g[1]; o0.z=g[2]; o0.w=g[3];   // l+0..7
  uint4 o1; o1.x=g[4]; o1.y=g[5]; o1.z=g[6]; o1.w=g[7];   // l+8..15
  // xt2 index: d = dtb*64+rd; l-range = lt*64+lq*16 (16 consecutive l = one h)
  int P  = lt*2 + (lq >> 1);          // pair 0..63
  int h  = lq & 1;                    // 16-l half within pair
  int k2 = dtb*2 + (rd >> 5);         // 32-d block 0..15
  int xR = (rd >> 2) & 7;
  int xr = rd & 3;
  int L0 = xR*8 + ((xr*2    ) ^ (xR & 3));   // staging lane for l+0..7
  int L1 = xR*8 + ((xr*2 + 1) ^ (xR & 3));   // staging lane for l+8..15
  size_t blk = ((size_t)b * NP + P) * 16384 + (size_t)(h*16 + k2) * 512;
  *reinterpret_cast<uint4*>(xt2 + blk + L0*8) = o0;
  *reinterpret_cast<uint4*>(xt2 + blk + L1*8) = o1;
}

// ---- Fused: per WG 128 c-rows x 512 d, stream L in 32-l pairs ----
__global__ __launch_bounds__(512, 2) void fused_kernel(
    const unsigned char* __restrict__ Ub8,
    const unsigned char* __restrict__ xb8,
    const unsigned short* __restrict__ xt2,
    float* __restrict__ out) {
  extern __shared__ unsigned short lds[];
  float* den_s = reinterpret_cast<float*>(lds + DENu);  // [128]
  const unsigned char* lb = reinterpret_cast<const unsigned char*>(lds);

  int bid = blockIdx.x;
  int linear = (bid & 7) * (NWGn/8) + (bid >> 3);  // bijective XCD swizzle (1120=8*140)
  int b = linear / NCTn;
  int cblk = linear - b * NCTn;
  int c0 = cblk * CTn;

  int t = threadIdx.x;
  int lane = t & 63;
  int w = t >> 6;          // wave 0..7: G1 c-eighth; G2 (cq,dq)=(w>>2,w&3)
  int li = lane & 15;
  int lg = lane >> 4;
  int cq = w >> 2;
  int dq = w & 3;

  const unsigned char* xb8p = xb8 + (size_t)b * Ln * Dn;
  const unsigned short* xt2p = xt2 + (size_t)b * NP * 16384;

  // ---- staging lane-consts ----
  int l5 = lane >> 5;                 // xk fp8: row sub-index per issue
  int s16 = lane & 31;                // xk fp8: dest slot16 (16B units)

  // fp8 xk: 2 issues/wave; rows rl = w*4 + 2i + l5 (0..31);
  // slot16 s of row r holds chunk16 s^(r&15): src = ((s16 ^ (rl&15)) * 16)
#define STAGE_XK(P, SLOT)                                                     \
  { _Pragma("unroll")                                                         \
    for (int i = 0; i < 2; ++i) {                                             \
      int rl = w*4 + 2*i + l5;                                                \
      gload16((const unsigned short*)(xb8p +                                  \
                  (size_t)((P)*32 + rl) * 512 +                               \
                  (size_t)(((s16 ^ (rl & 15)) * 16))),                        \
              lds + XKu(SLOT) + (w*4 + 2*i) * 256);                           \
    } }
  // xt2: 4 issues/wave, each 1KB CONTIGUOUS (pre-tiled layout)
#define STAGE_XT(P, SLOT)                                                     \
  { _Pragma("unroll")                                                         \
    for (int h = 0; h < 2; ++h)                                               \
      _Pragma("unroll")                                                       \
      for (int i = 0; i < 2; ++i) {                                           \
        int k = w*2 + i;                                                      \
        gload16(xt2p + (size_t)(P) * 16384 + (size_t)(h*16 + k) * 512 + lane*8,\
                lds + XTu(SLOT) + h*8192 + k*512);                            \
      } }

  // U fp8 fragments for MX-scaled 16x16x128: rows c0 + w*16 + li;
  // step s needs 32 B/lane at K = s*128 + lg*32  (8 x dwordx4 loads)
  i32x8 us[4];
  {
    const unsigned char* up8 = Ub8 + (size_t)(c0 + w*16 + li) * 512;
    #pragma unroll
    for (int s = 0; s < 4; ++s) {
      i32x4 qa = *reinterpret_cast<const i32x4*>(up8 + s*128 + lg*32);
      i32x4 qb = *reinterpret_cast<const i32x4*>(up8 + s*128 + lg*32 + 16);
      us[s] = __builtin_shufflevector(qa, qb, 0, 1, 2, 3, 4, 5, 6, 7);
    }
  }
  __builtin_amdgcn_sched_barrier(0);   // pin U loads BEFORE staging (vmcnt ledger)

  // prologue: queue = [U(8), XK0(2), XT0(4)]
  STAGE_XK(0, 0);
  STAGE_XT(0, 0);

  f32x4 acc[4][8];   // c = cq*64 + rr*16 + lg*4 + j,  d = dq*128 + dt*16 + li
  #pragma unroll
  for (int i = 0; i < 4; ++i)
    #pragma unroll
    for (int j = 0; j < 8; ++j) acc[i][j] = (f32x4){0.f, 0.f, 0.f, 0.f};
  float dsum[4];
  #pragma unroll
  for (int j = 0; j < 4; ++j) dsum[j] = 0.f;

  // G2 lane-const offsets
  int g2slot = (((li & 3) << 1) | (lg & 1)) ^ ((li >> 2) & 3);
  int g2off = ((lg >> 1) ? 8192 : 0) + (dq*32 + (li >> 2))*64 + g2slot*8;
  int pboff = ((lg >> 1) ? 3072 : 0) + (cq*64 + li)*P_S + (lg & 1)*8;

  BARV(4);   // U + XK(0) landed; XT(0) in flight

  int st = 1;                         // XT stage slot = (p+1)%3
  for (int p = 0; p < NP; ++p) {
    // ---- stage next: XK(p+1) 1-ahead dbuf, XT(p+1) into rotating slot ----
    if (p + 1 < NP) {
      STAGE_XK(p + 1, (p + 1) & 1);
      STAGE_XT(p + 1, st);
    }

    // ---- G1(p): MX-scaled fp8 (4 K-steps of 128) from XK slot p&1 ----
    // chunks16 cp,cp+1 read as 2x ds_read_b128 at slots (cp^li), ((cp+1)^li):
    // quarter-wave = 16 distinct 16B slots = 32 banks x 2-way = free
    f32x4 a0 = (f32x4){0.f,0.f,0.f,0.f}, a1 = a0;
    {
      const unsigned char* x0 = lb + (p & 1) * 16384 + li*512;   // row li (l 0-15)
      const unsigned char* x1 = x0 + 8192;                       // row li+16
      __builtin_amdgcn_s_setprio(1);
      #pragma unroll
      for (int s = 0; s < 4; ++s) {
        int cp = s*8 + lg*2;                   // base chunk16 (16B units)
        int o0 = ((cp    ) ^ li) * 16;
        int o1 = ((cp + 1) ^ li) * 16;
        i32x4 qa0 = *reinterpret_cast<const i32x4*>(x0 + o0);
        i32x4 qb0 = *reinterpret_cast<const i32x4*>(x0 + o1);
        i32x8 bv0 = __builtin_shufflevector(qa0, qb0, 0, 1, 2, 3, 4, 5, 6, 7);
        a0 = __builtin_amdgcn_mfma_scale_f32_16x16x128_f8f6f4(
                 us[s], bv0, a0, 0, 0, 0, 0x7F7F7F7F, 0, 0x7F7F7F7F);
        i32x4 qa1 = *reinterpret_cast<const i32x4*>(x1 + o0);
        i32x4 qb1 = *reinterpret_cast<const i32x4*>(x1 + o1);
        i32x8 bv1 = __builtin_shufflevector(qa1, qb1, 0, 1, 2, 3, 4, 5, 6, 7);
        a1 = __builtin_amdgcn_mfma_scale_f32_16x16x128_f8f6f4(
                 us[s], bv1, a1, 0, 0, 0, 0x7F7F7F7F, 0, 0x7F7F7F7F);
      }
      __builtin_amdgcn_s_setprio(0);
    }

    // ---- G2(p-1): bf16 GEMM2 from XT slot (p-1)%3 + P slot (p-1)&1 ----
    if (p > 0) {
      int xtrd = (st == 2) ? 0 : st + 1;       // (p-1)%3 == (st+1)%3
      const unsigned short* xbase = lds + XTu(xtrd) + g2off;
      const unsigned short* pws = lds + Pu((p - 1) & 1) + pboff;
      bf16x8 pa[4];
      #pragma unroll
      for (int rr = 0; rr < 4; ++rr)
        pa[rr] = *reinterpret_cast<const bf16x8*>(pws + rr*16*P_S);
      __builtin_amdgcn_s_setprio(1);
      #pragma unroll
      for (int dt = 0; dt < 8; ++dt) {
        bf16x8 bv = *reinterpret_cast<const bf16x8*>(xbase + dt*256);
        #pragma unroll
        for (int rr = 0; rr < 4; ++rr)
          acc[rr][dt] = __builtin_amdgcn_mfma_f32_16x16x32_bf16(
              pa[rr], bv, acc[rr][dt], 0, 0, 0);
      }
      __builtin_amdgcn_s_setprio(0);
    }

    // ---- softmax-finish(p) -> P slot p&1 ----
    {
      unsigned short* pw0 = lds + Pu(p & 1);
      unsigned short* pw1 = pw0 + 3072;
      #pragma unroll
      for (int j = 0; j < 4; ++j) {
        float pv0 = __expf(a0[j] * 0.0625f);   // undo U*16
        float pv1 = __expf(a1[j] * 0.0625f);
        dsum[j] += pv0 + pv1;
        pw0[(w*16 + lg*4 + j)*P_S + li] = f2bf(pv0);
        pw1[(w*16 + lg*4 + j)*P_S + li] = f2bf(pv1);
      }
    }

    // ---- single barrier per pair ----
    if (p + 1 < NP) { BARV(4); } else { BARV(0); }
    st = (st == 2) ? 0 : st + 1;
  }

  // ---- post-loop G2(NP-1): XT slot (NP-1)%3 = 0, P slot (NP-1)&1 = 1 ----
  {
    const unsigned short* xbase = lds + XTu(0) + g2off;
    const unsigned short* pws = lds + Pu(1) + pboff;
    bf16x8 pa[4];
    #pragma unroll
    for (int rr = 0; rr < 4; ++rr)
      pa[rr] = *reinterpret_cast<const bf16x8*>(pws + rr*16*P_S);
    __builtin_amdgcn_s_setprio(1);
    #pragma unroll
    for (int dt = 0; dt < 8; ++dt) {
      bf16x8 bv = *reinterpret_cast<const bf16x8*>(xbase + dt*256);
      #pragma unroll
      for (int rr = 0; rr < 4; ++rr)
        acc[rr][dt] = __builtin_amdgcn_mfma_f32_16x16x32_bf16(
            pa[rr], bv, acc[rr][dt], 0, 0, 0);
    }
    __builtin_amdgcn_s_setprio(0);
  }

  // denom: reduce over 16 l-lanes (li bits); each wave owns its 16 c rows
  #pragma unroll
  for (int m = 1; m < 16; m <<= 1)
    #pragma unroll
    for (int j = 0; j < 4; ++j)
      dsum[j] += __shfl_xor(dsum[j], m, 64);
  if (li == 0) {
    #pragma unroll
    for (int j = 0; j < 4; ++j)
      den_s[w*16 + lg*4 + j] = dsum[j];
  }
  __syncthreads();   // den ready; all G2 LDS reads done

  // epilogue: divide, per-wave LDS transpose (dead xk/xt area), 512B stores
  {
    float* er = reinterpret_cast<float*>(lds) + w * (16 * ER_S);
    int csub0 = lane >> 5;          // 0..1
    int dcol = (lane & 31) * 4;
    #pragma unroll
    for (int rr = 0; rr < 4; ++rr) {
      __syncthreads();   // er region free
      #pragma unroll
      for (int j = 0; j < 4; ++j) {
        int row = lg*4 + j;
        float inv = 1.0f / den_s[cq*64 + rr*16 + row];
        #pragma unroll
        for (int dt = 0; dt < 8; ++dt)
          er[row*ER_S + dt*16 + li] = acc[rr][dt][j] * inv;
      }
      __syncthreads();   // er ready
      #pragma unroll
      for (int it = 0; it < 8; ++it) {
        int crow = it*2 + csub0;
        float4 v = *reinterpret_cast<const float4*>(&er[crow*ER_S + dcol]);
        int c = c0 + cq*64 + rr*16 + crow;
        if (c < Cn)
          *reinterpret_cast<float4*>(out + ((size_t)b*Cn + c)*Dn + dq*128 + dcol) = v;
      }
    }
  }
}

extern "C" void kernel_launch(void* const* d_in, const int* in_sizes, int n_in,
                              void* d_out, int out_size, void* d_ws, size_t ws_size,
                              hipStream_t stream) {
  const float* x = (const float*)d_in[0];
  const float* U = (const float*)d_in[1];
  float* out = (float*)d_out;

  // ws layout: Ub8[8960*512 B] | xb8[16*2048*512 B] | xt2 bf16[16*64*16384] ~ 53 MB
  unsigned char* Ub8 = (unsigned char*)d_ws;
  unsigned char* xb8 = Ub8 + (size_t)CPn * Dn;
  unsigned short* xt2 = (unsigned short*)(xb8 + (size_t)Bn * Ln * Dn);

  hipFuncSetAttribute((const void*)fused_kernel,
                      hipFuncAttributeMaxDynamicSharedMemorySize, LDS_BYTES);

  cvt_u_kernel<<<(CPn*Dn)/(256*8), 256, 0, stream>>>(U, Ub8);
  cvt_x_kernel<<<Bn*32*8, 256, 0, stream>>>(x, xb8, xt2);
  fused_kernel<<<NWGn, 512, LDS_BYTES, stream>>>(Ub8, xb8, xt2, out);
}